// Round 1
// baseline (5017.384 us; speedup 1.0000x reference)
//
#include <hip/hip_runtime.h>
#include <math.h>

// RNNLayer: out[t] = tanh(x[t] @ Wx + b + h_{t-1} @ Wh), h_{-1} = h0
// S=128, B=128, D=1024, all fp32.
//
// Structure:
//   Phase 1: gemm_xp writes xp = x@Wx + b directly into d_out (same layout).
//   Phase 2: 128 sequential rnn_step launches, in-place on d_out:
//            out[t] = tanh(out[t](=xp_t) + out[t-1](=h_{t-1}) @ Wh).
//            Safe: each element of out[t] is read (as xp) only by the thread
//            that writes it (as h).

#define DIM 1024
#define BATCH 128
#define SEQ 128

// ---------------------------------------------------------------------------
// Phase 1: C[M,1024] = A[M,1024] @ W[1024,1024] + bias, M = S*B = 16384
// 64x64 tile, 256 threads, 4x4 micro-tile, BK=32.
// ---------------------------------------------------------------------------
__global__ __launch_bounds__(256) void gemm_xp(
    const float* __restrict__ A, const float* __restrict__ W,
    const float* __restrict__ bias, float* __restrict__ C)
{
    // padded to 68 floats/row: keeps float4 16B alignment, breaks stride-64 conflicts
    __shared__ float As[32][68];   // [k][m]
    __shared__ float Ws[32][68];   // [k][n]

    const int tid  = threadIdx.x;
    const int trow = tid / 16;       // 0..15 -> output rows trow*4..+3
    const int tcol = tid % 16;       // 0..15 -> output cols tcol*4..+3
    const int rowBase = blockIdx.y * 64;
    const int colBase = blockIdx.x * 64;

    // A-tile load mapping: 64 rows x 8 float4 (k), 2 rows per thread
    const int lam = tid / 8;         // 0..31
    const int laf = tid % 8;         // float4 index along k
    // W-tile load mapping: 32 k-rows x 16 float4 (n), 2 k-rows per thread
    const int lwk = tid / 16;        // 0..15
    const int lwf = tid % 16;        // float4 index along n

    float acc[4][4];
    #pragma unroll
    for (int i = 0; i < 4; ++i)
        #pragma unroll
        for (int j = 0; j < 4; ++j) acc[i][j] = 0.f;

    for (int k0 = 0; k0 < DIM; k0 += 32) {
        // stage A (transposed to [k][m])
        #pragma unroll
        for (int rr = 0; rr < 2; ++rr) {
            const int m = lam + rr * 32;
            const float4 v = *(const float4*)&A[(size_t)(rowBase + m) * DIM + k0 + laf * 4];
            As[laf * 4 + 0][m] = v.x;
            As[laf * 4 + 1][m] = v.y;
            As[laf * 4 + 2][m] = v.z;
            As[laf * 4 + 3][m] = v.w;
        }
        // stage W ([k][n], no transpose)
        #pragma unroll
        for (int rr = 0; rr < 2; ++rr) {
            const int k = lwk + rr * 16;
            *(float4*)&Ws[k][lwf * 4] =
                *(const float4*)&W[(size_t)(k0 + k) * DIM + colBase + lwf * 4];
        }
        __syncthreads();

        #pragma unroll
        for (int kk = 0; kk < 32; ++kk) {
            const float4 a4 = *(const float4*)&As[kk][trow * 4];
            const float4 w4 = *(const float4*)&Ws[kk][tcol * 4];
            const float av[4] = {a4.x, a4.y, a4.z, a4.w};
            const float wv[4] = {w4.x, w4.y, w4.z, w4.w};
            #pragma unroll
            for (int i = 0; i < 4; ++i)
                #pragma unroll
                for (int j = 0; j < 4; ++j)
                    acc[i][j] += av[i] * wv[j];
        }
        __syncthreads();
    }

    #pragma unroll
    for (int i = 0; i < 4; ++i) {
        const int row = rowBase + trow * 4 + i;
        const int col = colBase + tcol * 4;
        const float4 bv = *(const float4*)&bias[col];
        float4 o;
        o.x = acc[i][0] + bv.x;
        o.y = acc[i][1] + bv.y;
        o.z = acc[i][2] + bv.z;
        o.w = acc[i][3] + bv.w;
        *(float4*)&C[(size_t)row * DIM + col] = o;
    }
}

// ---------------------------------------------------------------------------
// Phase 2 step: hout = tanh(xp_t + hprev @ Wh), in place (hout aliases xp_t).
// Tile: 16 batch rows x 64 cols per WG -> grid (16, 8) = 128 WGs.
// h staged in LDS; Wh streamed from global (L2-resident, 4 MiB).
// ---------------------------------------------------------------------------
__global__ __launch_bounds__(256) void rnn_step(
    const float* __restrict__ hprev,  // [128,1024]
    const float* __restrict__ Wh,     // [1024,1024] row-major [k][n]
    float* __restrict__ hout)         // [128,1024], element [i] holds xp on entry
{
    __shared__ float hs[16][132];     // 16 rows x 128 k-chunk, padded

    const int tid = threadIdx.x;
    const int c4  = tid % 16;         // float4 col group
    const int r   = tid / 16;         // 0..15 batch row within tile
    const int rBase = blockIdx.y * 16;
    const int cBase = blockIdx.x * 64;

    float4 acc = {0.f, 0.f, 0.f, 0.f};

    for (int k0 = 0; k0 < DIM; k0 += 128) {
        // stage h tile: 16 rows x 128 k = 512 float4, 2 per thread
        {
            const int f  = tid % 32;  // float4 index along k
            const int rr = tid / 32;  // 0..7
            #pragma unroll
            for (int q = 0; q < 2; ++q) {
                const int row = rr + q * 8;
                *(float4*)&hs[row][f * 4] =
                    *(const float4*)&hprev[(size_t)(rBase + row) * DIM + k0 + f * 4];
            }
        }
        __syncthreads();

        #pragma unroll 4
        for (int kk = 0; kk < 128; kk += 4) {
            const float4 a4 = *(const float4*)&hs[r][kk];
            const float av[4] = {a4.x, a4.y, a4.z, a4.w};
            #pragma unroll
            for (int u = 0; u < 4; ++u) {
                const float4 w4 =
                    *(const float4*)&Wh[(size_t)(k0 + kk + u) * DIM + cBase + c4 * 4];
                acc.x += av[u] * w4.x;
                acc.y += av[u] * w4.y;
                acc.z += av[u] * w4.z;
                acc.w += av[u] * w4.w;
            }
        }
        __syncthreads();
    }

    const int row = rBase + r;
    const int col = cBase + c4 * 4;
    const float4 xpv = *(const float4*)&hout[(size_t)row * DIM + col];
    float4 o;
    o.x = tanhf(acc.x + xpv.x);
    o.y = tanhf(acc.y + xpv.y);
    o.z = tanhf(acc.z + xpv.z);
    o.w = tanhf(acc.w + xpv.w);
    *(float4*)&hout[(size_t)row * DIM + col] = o;
}

// ---------------------------------------------------------------------------
extern "C" void kernel_launch(void* const* d_in, const int* in_sizes, int n_in,
                              void* d_out, int out_size, void* d_ws, size_t ws_size,
                              hipStream_t stream) {
    const float* x  = (const float*)d_in[0];   // [S,B,D]
    const float* h0 = (const float*)d_in[1];   // [B,D]
    const float* Wx = (const float*)d_in[2];   // [D,D]
    const float* Wh = (const float*)d_in[3];   // [D,D]
    const float* b  = (const float*)d_in[4];   // [D]
    float* out = (float*)d_out;                // [S,B,D]

    // Phase 1: out = x @ Wx + b  (M = S*B = 16384)
    gemm_xp<<<dim3(DIM / 64, (SEQ * BATCH) / 64), 256, 0, stream>>>(x, Wx, b, out);

    // Phase 2: 128 sequential steps, in place
    for (int t = 0; t < SEQ; ++t) {
        const float* hprev = (t == 0) ? h0 : out + (size_t)(t - 1) * BATCH * DIM;
        float* hout = out + (size_t)t * BATCH * DIM;
        rnn_step<<<dim3(DIM / 64, BATCH / 16), 256, 0, stream>>>(hprev, Wh, hout);
    }
}